// Round 1
// baseline (628.555 us; speedup 1.0000x reference)
//
#include <hip/hip_runtime.h>

#define S_TOK 4096
#define DMODEL 1024
#define HDIM 4096
#define NEXP 8
#define CAPACITY 1280

struct TokenRoute { int e1, p1, e2, p2; float w1, w2; };

typedef __bf16 bf16x8 __attribute__((ext_vector_type(8)));
typedef float f32x4 __attribute__((ext_vector_type(4)));

__device__ __forceinline__ unsigned short f2bf(float f) {
    unsigned int u = __float_as_uint(f);
    unsigned int r = 0x7fffu + ((u >> 16) & 1u);
    return (unsigned short)((u + r) >> 16);
}
__device__ __forceinline__ float bf2f(unsigned short b) {
    return __uint_as_float(((unsigned int)b) << 16);
}

__device__ __forceinline__ void gload16(const void* gsrc, void* ldst) {
    __builtin_amdgcn_global_load_lds(
        (const __attribute__((address_space(1))) unsigned int*)gsrc,
        (__attribute__((address_space(3))) unsigned int*)ldst, 16, 0, 0);
}

__device__ __forceinline__ float gelu_tanh(float x) {
    float u = 0.7978845608028654f * (x + 0.044715f * x * x * x);
    return 0.5f * x * (1.0f + tanhf(u));
}

// ---------------- transpose + fp32->bf16 convert: src [E][R][C] f32 -> dst [E][C][R] bf16
__global__ void transpose_cvt(const float* __restrict__ src, unsigned short* __restrict__ dst,
                              int R, int C) {
    __shared__ unsigned short t[64][68];
    size_t eoff = (size_t)blockIdx.z * R * C;
    src += eoff; dst += eoff;
    int r0 = blockIdx.y * 64, c0 = blockIdx.x * 64;
    int tid = threadIdx.x;
    int rr = tid >> 2, q = tid & 3;
#pragma unroll
    for (int s = 0; s < 4; ++s) {
        const float4 v = *(const float4*)(src + (size_t)(r0 + rr) * C + c0 + q * 16 + s * 4);
        int cc = q * 16 + s * 4;
        t[rr][cc + 0] = f2bf(v.x); t[rr][cc + 1] = f2bf(v.y);
        t[rr][cc + 2] = f2bf(v.z); t[rr][cc + 3] = f2bf(v.w);
    }
    __syncthreads();
#pragma unroll
    for (int s = 0; s < 4; ++s) {
        int rb = q * 16 + s * 4;
        ushort4 o;
        o.x = t[rb + 0][rr]; o.y = t[rb + 1][rr]; o.z = t[rb + 2][rr]; o.w = t[rb + 3][rr];
        *(ushort4*)(dst + (size_t)(c0 + rr) * R + r0 + rb) = o;
    }
}

// ---------------- gating: logits, softmax, top-2. One 64-lane block per token.
__global__ void gate_kernel(const float* __restrict__ tokens, const float* __restrict__ gw,
                            float* __restrict__ gates, TokenRoute* __restrict__ route) {
    int s = blockIdx.x, l = threadIdx.x;
    const float* x = tokens + (size_t)s * DMODEL;
    float p[NEXP];
#pragma unroll
    for (int e = 0; e < NEXP; ++e) p[e] = 0.f;
#pragma unroll
    for (int it = 0; it < 4; ++it) {
        int i = (it * 64 + l) * 4;
        float4 v = *(const float4*)(x + i);
#pragma unroll
        for (int e = 0; e < NEXP; ++e) {
            float4 g = *(const float4*)(gw + e * DMODEL + i);
            p[e] += v.x * g.x + v.y * g.y + v.z * g.z + v.w * g.w;
        }
    }
#pragma unroll
    for (int e = 0; e < NEXP; ++e) {
        float v = p[e];
        v += __shfl_xor(v, 32); v += __shfl_xor(v, 16); v += __shfl_xor(v, 8);
        v += __shfl_xor(v, 4);  v += __shfl_xor(v, 2);  v += __shfl_xor(v, 1);
        p[e] = v;
    }
    // top-2 on logits (== top-2 on gates, softmax monotone; first-index tie rule)
    int e1 = 0; float b1v = p[0];
#pragma unroll
    for (int e = 1; e < NEXP; ++e) if (p[e] > b1v) { b1v = p[e]; e1 = e; }
    int e2 = -1; float b2v = -3.0e38f;
#pragma unroll
    for (int e = 0; e < NEXP; ++e) if (e != e1 && p[e] > b2v) { b2v = p[e]; e2 = e; }
    // softmax
    float mx = p[0];
#pragma unroll
    for (int e = 1; e < NEXP; ++e) mx = fmaxf(mx, p[e]);
    float sum = 0.f;
#pragma unroll
    for (int e = 0; e < NEXP; ++e) { p[e] = __expf(p[e] - mx); sum += p[e]; }
    float inv = 1.0f / sum;
#pragma unroll
    for (int e = 0; e < NEXP; ++e) p[e] *= inv;
    float g1 = __expf(b1v - mx) * inv;
    float g2 = __expf(b2v - mx) * inv;
    if (l == 0) {
        float* gp = gates + (size_t)s * NEXP;
#pragma unroll
        for (int e = 0; e < NEXP; ++e) gp[e] = p[e];
        TokenRoute r; r.e1 = e1; r.p1 = 0; r.e2 = e2; r.p2 = 0; r.w1 = g1; r.w2 = g2;
        route[s] = r;
    }
}

// ---------------- routing scan: cumsum positions, capacity, weights, counts, l_aux
__global__ void route_scan(TokenRoute* __restrict__ route, const float* __restrict__ gates,
                           int* __restrict__ cnt, float* __restrict__ laux_out) {
    __shared__ unsigned int buf[1024][NEXP];   // 32 KB
    int t = threadIdx.x;
    int te1[4], te2[4]; float tg1[4], tg2[4];
    unsigned int c1[NEXP], c2[NEXP];
#pragma unroll
    for (int e = 0; e < NEXP; ++e) { c1[e] = 0; c2[e] = 0; }
    for (int j = 0; j < 4; ++j) {
        TokenRoute r = route[t * 4 + j];
        te1[j] = r.e1; te2[j] = r.e2; tg1[j] = r.w1; tg2[j] = r.w2;
#pragma unroll
        for (int e = 0; e < NEXP; ++e) { c1[e] += (r.e1 == e); c2[e] += (r.e2 == e); }
    }
    // inclusive scan of c1
#pragma unroll
    for (int e = 0; e < NEXP; ++e) buf[t][e] = c1[e];
    __syncthreads();
    for (int off = 1; off < 1024; off <<= 1) {
        unsigned int v[NEXP];
#pragma unroll
        for (int e = 0; e < NEXP; ++e) v[e] = (t >= off) ? buf[t - off][e] : 0u;
        __syncthreads();
#pragma unroll
        for (int e = 0; e < NEXP; ++e) buf[t][e] += v[e];
        __syncthreads();
    }
    unsigned int ex1[NEXP], tot1[NEXP];
#pragma unroll
    for (int e = 0; e < NEXP; ++e) { ex1[e] = buf[t][e] - c1[e]; tot1[e] = buf[1023][e]; }
    __syncthreads();
    // inclusive scan of c2
#pragma unroll
    for (int e = 0; e < NEXP; ++e) buf[t][e] = c2[e];
    __syncthreads();
    for (int off = 1; off < 1024; off <<= 1) {
        unsigned int v[NEXP];
#pragma unroll
        for (int e = 0; e < NEXP; ++e) v[e] = (t >= off) ? buf[t - off][e] : 0u;
        __syncthreads();
#pragma unroll
        for (int e = 0; e < NEXP; ++e) buf[t][e] += v[e];
        __syncthreads();
    }
    unsigned int ex2[NEXP], tot2[NEXP];
#pragma unroll
    for (int e = 0; e < NEXP; ++e) { ex2[e] = buf[t][e] - c2[e]; tot2[e] = buf[1023][e]; }
    __syncthreads();
    // gate sums for l_aux
    float gs[NEXP];
#pragma unroll
    for (int e = 0; e < NEXP; ++e) gs[e] = 0.f;
    for (int j = 0; j < 4; ++j) {
        const float* gp = gates + (size_t)(t * 4 + j) * NEXP;
#pragma unroll
        for (int e = 0; e < NEXP; ++e) gs[e] += gp[e];
    }
    float* fb = (float*)&buf[0][0];
#pragma unroll
    for (int e = 0; e < NEXP; ++e) fb[t * NEXP + e] = gs[e];
    __syncthreads();
    for (int off = 512; off > 0; off >>= 1) {
        if (t < off) {
#pragma unroll
            for (int e = 0; e < NEXP; ++e) fb[t * NEXP + e] += fb[(t + off) * NEXP + e];
        }
        __syncthreads();
    }
    if (t == 0) {
        float laux = 0.f;
#pragma unroll
        for (int e = 0; e < NEXP; ++e) {
            laux += (fb[e] / (float)S_TOK) * ((float)tot1[e] / (float)S_TOK);
            int c = (int)(tot1[e] + tot2[e]);
            cnt[e] = c < CAPACITY ? c : CAPACITY;
        }
        *laux_out = laux * (float)NEXP;
    }
    // final per-token positions + weights
    unsigned int r1[NEXP], r2[NEXP];
#pragma unroll
    for (int e = 0; e < NEXP; ++e) { r1[e] = 0; r2[e] = 0; }
    for (int j = 0; j < 4; ++j) {
        int E1 = te1[j], E2 = te2[j];
        unsigned int loc1 = 0, loc2 = 0;
#pragma unroll
        for (int e = 0; e < NEXP; ++e) if (E1 == e) { loc1 = ex1[e] + r1[e]; r1[e]++; }
#pragma unroll
        for (int e = 0; e < NEXP; ++e) if (E2 == e) { loc2 = ex2[e] + r2[e] + tot1[e]; r2[e]++; }
        bool k1 = loc1 < CAPACITY, k2 = loc2 < CAPACITY;
        float G1 = k1 ? tg1[j] : 0.f;
        float G2 = k2 ? tg2[j] : 0.f;
        float denom = fmaxf(G1 + G2, 1.1920929e-07f);
        TokenRoute r;
        r.e1 = E1; r.p1 = k1 ? (int)loc1 : -1;
        r.e2 = E2; r.p2 = k2 ? (int)loc2 : -1;
        r.w1 = G1 / denom; r.w2 = G2 / denom;
        route[t * 4 + j] = r;
    }
}

// ---------------- dispatch scatter: tokens -> disp[e][pos][:] (bf16)
__global__ void dispatch_scatter(const float* __restrict__ tokens, const TokenRoute* __restrict__ route,
                                 unsigned short* __restrict__ disp) {
    int s = blockIdx.x, l = threadIdx.x;
    TokenRoute r = route[s];
    const float* x = tokens + (size_t)s * DMODEL;
    ushort4 vals[4];
#pragma unroll
    for (int q = 0; q < 4; ++q) {
        float4 v = *(const float4*)(x + (q * 64 + l) * 4);
        vals[q].x = f2bf(v.x); vals[q].y = f2bf(v.y); vals[q].z = f2bf(v.z); vals[q].w = f2bf(v.w);
    }
    if (r.p1 >= 0) {
        unsigned short* d = disp + ((size_t)r.e1 * CAPACITY + r.p1) * DMODEL;
#pragma unroll
        for (int q = 0; q < 4; ++q) *(ushort4*)(d + (q * 64 + l) * 4) = vals[q];
    }
    if (r.p2 >= 0) {
        unsigned short* d = disp + ((size_t)r.e2 * CAPACITY + r.p2) * DMODEL;
#pragma unroll
        for (int q = 0; q < 4; ++q) *(ushort4*)(d + (q * 64 + l) * 4) = vals[q];
    }
}

// ---------------- bf16 GEMM: C[M,N] = A[M,K] * Bt[N,K]^T (+bias, optional gelu)
// 128x128 tile, BK=32, 4 waves 2x2, 16x16x32 MFMA, global_load_lds + XOR swizzle.
template <int MODE>  // 0: gelu(x+bias) -> bf16 ; 1: x+bias -> bf16
__global__ __launch_bounds__(256)
void gemm_bt(const unsigned short* __restrict__ A, const unsigned short* __restrict__ Bt,
             unsigned short* __restrict__ C, const float* __restrict__ bias,
             const int* __restrict__ cnt,
             int N, int K, int Ntiles,
             size_t strideAe, size_t strideBe, size_t strideCe, int biasStride) {
    int e = blockIdx.z;
    int mt = blockIdx.x / Ntiles, nt = blockIdx.x % Ntiles;
    if (mt * 128 >= cnt[e]) return;
    const unsigned short* Ae = A + (size_t)e * strideAe;
    const unsigned short* Be = Bt + (size_t)e * strideBe;
    unsigned short* Ce = C + (size_t)e * strideCe;
    const float* be = bias + (size_t)e * biasStride;

    __shared__ unsigned short sA[2][4096];
    __shared__ unsigned short sB[2][4096];

    int tid = threadIdx.x;
    int w = tid >> 6, lane = tid & 63;
    int wm = w >> 1, wn = w & 1;
    int lr = lane & 15, kc = lane >> 4;
    int srow = lane >> 2, scp = lane & 3;

    f32x4 acc[4][4];
#pragma unroll
    for (int m = 0; m < 4; ++m)
#pragma unroll
        for (int n = 0; n < 4; ++n) acc[m][n] = (f32x4){0.f, 0.f, 0.f, 0.f};

    int nk = K >> 5;
    int swz = ((lr ^ (lr >> 2)) & 3);
    int fA = (wm * 64 + lr) * 32 + ((kc ^ swz) * 8);
    int fB = (wn * 64 + lr) * 32 + ((kc ^ swz) * 8);

    auto stage = [&](int bufi, int kt) {
#pragma unroll
        for (int p = 0; p < 2; ++p) {
            int inst = w * 2 + p;
            int row = inst * 16 + srow;
            int c = scp ^ ((row ^ (row >> 2)) & 3);
            const unsigned short* ga = Ae + (size_t)(mt * 128 + row) * K + kt * 32 + c * 8;
            gload16(ga, &sA[bufi][inst * 512]);
            const unsigned short* gb = Be + (size_t)(nt * 128 + row) * K + kt * 32 + c * 8;
            gload16(gb, &sB[bufi][inst * 512]);
        }
    };

    stage(0, 0);
    int buf = 0;
    for (int kt = 0; kt < nk; ++kt) {
        __syncthreads();
        if (kt + 1 < nk) stage(buf ^ 1, kt + 1);
        bf16x8 av[4], bv[4];
#pragma unroll
        for (int m = 0; m < 4; ++m) av[m] = *(const bf16x8*)&sA[buf][fA + m * 512];
#pragma unroll
        for (int n = 0; n < 4; ++n) bv[n] = *(const bf16x8*)&sB[buf][fB + n * 512];
#pragma unroll
        for (int m = 0; m < 4; ++m)
#pragma unroll
            for (int n = 0; n < 4; ++n)
                acc[m][n] = __builtin_amdgcn_mfma_f32_16x16x32_bf16(av[m], bv[n], acc[m][n], 0, 0, 0);
        buf ^= 1;
    }

    int orow0 = mt * 128 + wm * 64 + (lane >> 4) * 4;
    int ocol0 = nt * 128 + wn * 64 + lr;
#pragma unroll
    for (int m = 0; m < 4; ++m) {
#pragma unroll
        for (int n = 0; n < 4; ++n) {
            int col = ocol0 + n * 16;
            float bvv = be[col];
#pragma unroll
            for (int r = 0; r < 4; ++r) {
                int row = orow0 + m * 16 + r;
                float v = acc[m][n][r] + bvv;
                if (MODE == 0) v = gelu_tanh(v);
                Ce[(size_t)row * N + col] = f2bf(v);
            }
        }
    }
}

// ---------------- combine: out[s] = w1*eout[e1,p1] + w2*eout[e2,p2]
__global__ void combine_kernel(const TokenRoute* __restrict__ route, const unsigned short* __restrict__ eout,
                               float* __restrict__ out) {
    int s = blockIdx.x, l = threadIdx.x;
    TokenRoute r = route[s];
    bool v1 = r.p1 >= 0, v2 = r.p2 >= 0;
#pragma unroll
    for (int q = 0; q < 4; ++q) {
        int i = (q * 64 + l) * 4;
        float4 a = {0.f, 0.f, 0.f, 0.f};
        if (v1) {
            const unsigned short* p = eout + ((size_t)r.e1 * CAPACITY + r.p1) * DMODEL + i;
            ushort4 u = *(const ushort4*)p;
            a.x += r.w1 * bf2f(u.x); a.y += r.w1 * bf2f(u.y);
            a.z += r.w1 * bf2f(u.z); a.w += r.w1 * bf2f(u.w);
        }
        if (v2) {
            const unsigned short* p = eout + ((size_t)r.e2 * CAPACITY + r.p2) * DMODEL + i;
            ushort4 u = *(const ushort4*)p;
            a.x += r.w2 * bf2f(u.x); a.y += r.w2 * bf2f(u.y);
            a.z += r.w2 * bf2f(u.z); a.w += r.w2 * bf2f(u.w);
        }
        *(float4*)(out + (size_t)s * DMODEL + i) = a;
    }
}

extern "C" void kernel_launch(void* const* d_in, const int* in_sizes, int n_in,
                              void* d_out, int out_size, void* d_ws, size_t ws_size,
                              hipStream_t stream) {
    const float* inputs = (const float*)d_in[0];
    const float* gw     = (const float*)d_in[1];
    const float* w1     = (const float*)d_in[2];
    const float* b1     = (const float*)d_in[3];
    const float* w2     = (const float*)d_in[4];
    const float* b2     = (const float*)d_in[5];
    float* out = (float*)d_out;

    char* ws = (char*)d_ws;
    const size_t SZ_W = (size_t)NEXP * DMODEL * HDIM * 2;           // 64 MiB each
    const size_t SZ_DISP = (size_t)NEXP * CAPACITY * DMODEL * 2;    // 20 MiB
    const size_t SZ_H = (size_t)NEXP * CAPACITY * HDIM * 2;         // 80 MiB
    unsigned short* wb1t = (unsigned short*)(ws);
    unsigned short* wb2t = (unsigned short*)(ws + SZ_W);
    unsigned short* disp = (unsigned short*)(ws + 2 * SZ_W);        // aliased: eout after GEMM1
    unsigned short* h    = (unsigned short*)(ws + 2 * SZ_W + SZ_DISP);
    float* gates = (float*)(ws + 2 * SZ_W + SZ_DISP + SZ_H);
    TokenRoute* route = (TokenRoute*)(ws + 2 * SZ_W + SZ_DISP + SZ_H + (size_t)S_TOK * NEXP * 4);
    int* cnt = (int*)((char*)route + (size_t)S_TOK * sizeof(TokenRoute));

    // w1 [E][D][H] -> wb1t [E][H][D]; w2 [E][H][D] -> wb2t [E][D][H]
    transpose_cvt<<<dim3(HDIM / 64, DMODEL / 64, NEXP), 256, 0, stream>>>(w1, wb1t, DMODEL, HDIM);
    transpose_cvt<<<dim3(DMODEL / 64, HDIM / 64, NEXP), 256, 0, stream>>>(w2, wb2t, HDIM, DMODEL);
    gate_kernel<<<S_TOK, 64, 0, stream>>>(inputs, gw, gates, route);
    route_scan<<<1, 1024, 0, stream>>>(route, gates, cnt, out + (size_t)S_TOK * DMODEL);
    hipMemsetAsync(disp, 0, SZ_DISP, stream);
    dispatch_scatter<<<S_TOK, 64, 0, stream>>>(inputs, route, disp);
    // GEMM1: h = gelu(disp @ w1 + b1)   M=1280 N=4096 K=1024
    gemm_bt<0><<<dim3((CAPACITY / 128) * (HDIM / 128), 1, NEXP), 256, 0, stream>>>(
        disp, wb1t, h, b1, cnt, HDIM, DMODEL, HDIM / 128,
        (size_t)CAPACITY * DMODEL, (size_t)HDIM * DMODEL, (size_t)CAPACITY * HDIM, HDIM);
    // GEMM2: eout = h @ w2 + b2         M=1280 N=1024 K=4096  (eout aliases disp)
    gemm_bt<1><<<dim3((CAPACITY / 128) * (DMODEL / 128), 1, NEXP), 256, 0, stream>>>(
        h, wb2t, disp, b2, cnt, DMODEL, HDIM, DMODEL / 128,
        (size_t)CAPACITY * HDIM, (size_t)DMODEL * HDIM, (size_t)CAPACITY * DMODEL, DMODEL);
    combine_kernel<<<S_TOK, 64, 0, stream>>>(route, disp, out);
}